// Round 9
// baseline (286.409 us; speedup 1.0000x reference)
//
#include <hip/hip_runtime.h>
#include <hip/hip_bf16.h>

typedef __hip_bfloat16 bf16;
typedef __attribute__((ext_vector_type(8))) __bf16 bf16x8;
typedef __attribute__((ext_vector_type(4))) __bf16 bf16x4;
typedef __attribute__((ext_vector_type(4))) float f32x4;
typedef unsigned short u16;

#define MFMA16(a, b, c) __builtin_amdgcn_mfma_f32_16x16x32_bf16((a), (b), (c), 0, 0, 0)

static constexpr int B_ = 2, T_ = 2048, C_ = 1024, H_ = 16, D_ = 64;
static constexpr int BT = B_ * T_;   // 4096
static constexpr int N3 = 3 * C_;    // 3072

__device__ __forceinline__ void gload16(void* lds, const void* g) {
    __builtin_amdgcn_global_load_lds(
        (const __attribute__((address_space(1))) unsigned int*)g,
        (__attribute__((address_space(3))) unsigned int*)lds, 16, 0, 0);
}

__device__ __forceinline__ u16 bb(float x) {
    return __builtin_bit_cast(u16, __float2bfloat16(x));
}

// ---------- prep kernels ----------

// src (K rows, N cols) fp32 -> dst (N rows, K cols) bf16, tiled via LDS
__global__ void k_transpose_w(const float* __restrict__ src, bf16* __restrict__ dst,
                              int K, int N) {
    __shared__ float t[32][33];
    int bx = blockIdx.x * 32;  // n offset
    int by = blockIdx.y * 32;  // k offset
    int tx = threadIdx.x & 31, ty = threadIdx.x >> 5;  // 256 thr: ty 0..7
#pragma unroll
    for (int i = 0; i < 32; i += 8)
        t[ty + i][tx] = src[(size_t)(by + ty + i) * N + bx + tx];
    __syncthreads();
#pragma unroll
    for (int i = 0; i < 32; i += 8)
        dst[(size_t)(bx + ty + i) * K + by + tx] = __float2bfloat16(t[tx][ty + i]);
}

__global__ void k_convert_x(const float* __restrict__ src, bf16* __restrict__ dst, int n4) {
    int i = blockIdx.x * 256 + threadIdx.x;
    if (i >= n4) return;
    float4 v = reinterpret_cast<const float4*>(src)[i];
    dst[4 * i + 0] = __float2bfloat16(v.x);
    dst[4 * i + 1] = __float2bfloat16(v.y);
    dst[4 * i + 2] = __float2bfloat16(v.z);
    dst[4 * i + 3] = __float2bfloat16(v.w);
}

// cos/sin tables, (T, 32) each: ang = t * 10000^(-f/32)
__global__ void k_rope_table(float* __restrict__ ct, float* __restrict__ st) {
    int i = blockIdx.x * 256 + threadIdx.x;  // t*32 + f
    if (i >= T_ * 32) return;
    int t = i >> 5, f = i & 31;
    float invf = exp2f(-(float)f * 0.4152410118609203f);  // 10000^(-f/32)
    float ang = (float)t * invf;
    ct[i] = cosf(ang);
    st[i] = sinf(ang);
}

// ---------- QKV GEMM (m97 structure: global_load_lds w=16, linear LDS) ----------
__global__ __launch_bounds__(256) void k_gemm_qkv(
    const bf16* __restrict__ A, const bf16* __restrict__ Bt,
    const float* __restrict__ bias,
    const float* __restrict__ ct, const float* __restrict__ st,
    bf16* __restrict__ q, bf16* __restrict__ kk, bf16* __restrict__ vt) {
    __shared__ bf16 lA[128 * 32];
    __shared__ bf16 lB[128 * 32];
    const int tid = threadIdx.x;
    const int wave = tid >> 6, lane = tid & 63;
    const int wm = wave >> 1, wn = wave & 1;
    const int l16 = lane & 15, lg = lane >> 4;
    const int m0 = blockIdx.y * 128, n0 = blockIdx.x * 128;

    f32x4 acc[4][4];
#pragma unroll
    for (int i = 0; i < 4; i++)
#pragma unroll
        for (int j = 0; j < 4; j++) acc[i][j] = (f32x4){0.f, 0.f, 0.f, 0.f};

    const bf16* gA = A + (size_t)(m0 + wave * 32 + (lane >> 2)) * 1024 + (lane & 3) * 8;
    const bf16* gB = Bt + (size_t)(n0 + wave * 32 + (lane >> 2)) * 1024 + (lane & 3) * 8;
    bf16* sA = lA + wave * 1024;
    bf16* sB = lB + wave * 1024;

    for (int k0 = 0; k0 < 1024; k0 += 32) {
        __syncthreads();
        gload16(sA, gA + k0);
        gload16(sA + 512, gA + (size_t)16 * 1024 + k0);
        gload16(sB, gB + k0);
        gload16(sB + 512, gB + (size_t)16 * 1024 + k0);
        __syncthreads();
        bf16x8 af[4], bfr[4];
#pragma unroll
        for (int mi = 0; mi < 4; mi++)
            af[mi] = *(const bf16x8*)(lA + (wm * 64 + mi * 16 + l16) * 32 + lg * 8);
#pragma unroll
        for (int nj = 0; nj < 4; nj++)
            bfr[nj] = *(const bf16x8*)(lB + (wn * 64 + nj * 16 + l16) * 32 + lg * 8);
#pragma unroll
        for (int mi = 0; mi < 4; mi++)
#pragma unroll
            for (int nj = 0; nj < 4; nj++)
                acc[mi][nj] = MFMA16(af[mi], bfr[nj], acc[mi][nj]);
    }

    // epilogue: bias + RoPE + scatter
    const int b = m0 >> 11;
#pragma unroll
    for (int mi = 0; mi < 4; mi++) {
        int mbase = m0 + wm * 64 + mi * 16 + lg * 4;
#pragma unroll
        for (int nj = 0; nj < 4; nj++) {
            int n = n0 + wn * 64 + nj * 16 + l16;
            int which = n >> 10;        // 0=q 1=k 2=v (uniform per block)
            int nq = n & 1023;
            int h = nq >> 6, d = nq & 63;
#pragma unroll
            for (int r = 0; r < 4; r++) {
                int m = mbase + r;
                int t = m & 2047;
                float v = acc[mi][nj][r] + bias[n];
                if (which == 2) {
                    vt[((size_t)(b * 16 + h) * 64 + d) * 2048 + t] = __float2bfloat16(v);
                } else {
                    float pv = acc[mi][nj ^ 2][r] + bias[n ^ 32];  // partner d^32, same lane
                    float c = ct[t * 32 + (d & 31)];
                    float s = st[t * 32 + (d & 31)];
                    float rh = (d < 32) ? -pv : pv;
                    float o = v * c + rh * s;
                    bf16* dst = (which == 0) ? q : kk;
                    dst[((size_t)(b * 16 + h) * 2048 + t) * 64 + d] = __float2bfloat16(o);
                }
            }
        }
    }
}

// ---------- flash attention: 16 q-rows/wave + software-pipelined PV ----------
// Layout identical to R8 (R1-HW-proven 16x16x32):
//   S^T[kv][q] = mfma16(K, Q): C/D col=l16 (q), row=4lg+r (kv).
//   PV: O[d][q] = mfma16(V_perm, P_as_owned); V slot (lg,j) reads kv c(lg,j) =
//     {j<4: 4lg+j; j>=4: 16+4lg+(j&3)}.
// Pipeline per tile i: QK(i) -> PV(i-1) -> softmax(i).  PV(i-1) adds at scale
// m_{i-1}; softmax(i) rescales o AFTER -> online softmax stays exact.
// K prefetched 1 tile ahead; V(i) loaded during iter i, consumed at iter i+1.
// Numerics = R8 exactly (e-domain, post-MFMA 0.125 scale, always-rescale).
__global__ __launch_bounds__(256, 2) void k_attn(
    const bf16* __restrict__ qg, const bf16* __restrict__ kg,
    const bf16* __restrict__ vtg, bf16* __restrict__ y) {
    const int wave = threadIdx.x >> 6, lane = threadIdx.x & 63;
    const int l16 = lane & 15, lg = lane >> 4;
    const int bh = blockIdx.y;
    // strip remap: pair heavy strips with light ones across the bh halves
    const int strip = (bh < 16) ? (int)blockIdx.x : 31 - (int)blockIdx.x;
    const int q0 = strip * 64 + wave * 16;   // 16 rows per wave
    const int qmax = q0 + 15;
    const int qrow = q0 + l16;
    const bf16* qh = qg + (size_t)bh * (2048 * 64);
    const bf16* kh = kg + (size_t)bh * (2048 * 64);
    const bf16* vh = vtg + (size_t)bh * (64 * 2048);

    // Q B-frags (1 q-group x 2 d-halves), raw bf16
    bf16x8 qf[2];
#pragma unroll
    for (int h = 0; h < 2; h++)
        qf[h] = *(const bf16x8*)(qh + (size_t)qrow * 64 + 32 * h + 8 * lg);

    f32x4 o[4];
#pragma unroll
    for (int dt = 0; dt < 4; dt++) o[dt] = (f32x4){0.f, 0.f, 0.f, 0.f};
    float mm = -1e30f, ls = 0.f;

    bf16x8 kf[2][2], nkf[2][2], vfA[4], vfB[4], pfp;

    auto loadK = [&](int kt, bf16x8 kfo[2][2]) {
#pragma unroll
        for (int t = 0; t < 2; t++) {
            const bf16* kp = kh + (size_t)(kt + 16 * t + l16) * 64 + 8 * lg;
            kfo[t][0] = *(const bf16x8*)(kp);
            kfo[t][1] = *(const bf16x8*)(kp + 32);
        }
    };
    auto loadV = [&](int kt, bf16x8 vfo[4]) {
#pragma unroll
        for (int dt = 0; dt < 4; dt++) {
            const bf16* vp = vh + (size_t)(16 * dt + l16) * 2048 + kt;
            bf16x4 lo = *(const bf16x4*)(vp + 4 * lg);
            bf16x4 hi = *(const bf16x4*)(vp + 16 + 4 * lg);
            vfo[dt] = __builtin_shufflevector(lo, hi, 0, 1, 2, 3, 4, 5, 6, 7);
        }
    };

    const f32x4 z = (f32x4){0.f, 0.f, 0.f, 0.f};
    auto qk = [&](bf16x8 kfi[2][2], f32x4 s[2]) {
#pragma unroll
        for (int t = 0; t < 2; t++) {
            f32x4 acc = MFMA16(kfi[t][0], qf[0], z);
            s[t] = MFMA16(kfi[t][1], qf[1], acc);
        }
    };
    auto pv = [&](bf16x8 vfi[4], bf16x8 pf) {
#pragma unroll
        for (int dt = 0; dt < 4; dt++) o[dt] = MFMA16(vfi[dt], pf, o[dt]);
    };
    auto softmax = [&](f32x4 s[2], int kt, bool diag) -> bf16x8 {
        float p[8];
#pragma unroll
        for (int t = 0; t < 2; t++)
#pragma unroll
            for (int r = 0; r < 4; r++) {
                float v = s[t][r] * 0.125f;
                if (diag && (kt + 16 * t + 4 * lg + r > qrow)) v = -1e30f;
                p[4 * t + r] = v;
            }
        float pm = p[0];
#pragma unroll
        for (int i = 1; i < 8; i++) pm = fmaxf(pm, p[i]);
        pm = fmaxf(pm, __shfl_xor(pm, 16, 64));
        pm = fmaxf(pm, __shfl_xor(pm, 32, 64));
        float mn = fmaxf(mm, pm);
        float al = __expf(mm - mn);
#pragma unroll
        for (int dt = 0; dt < 4; dt++) o[dt] *= al;
        ls *= al;
        mm = mn;
        float ps = 0.f;
#pragma unroll
        for (int i = 0; i < 8; i++) {
            p[i] = __expf(p[i] - mn);
            ps += p[i];
        }
        ls += ps;
        bf16x8 pf;
#pragma unroll
        for (int j = 0; j < 8; j++)
            pf[j] = __builtin_bit_cast(__bf16, __float2bfloat16(p[j]));
        return pf;
    };

    f32x4 s[2];
    // ---- tile 0 (prologue) ----
    loadK(0, kf);
    if (qmax >= 32) loadK(32, nkf);
    loadV(0, vfB);                       // V0, consumed at iter kt=32 (or epilogue)
    qk(kf, s);
    pfp = softmax(s, 0, qmax < 32);
#pragma unroll
    for (int t = 0; t < 2; t++) { kf[t][0] = nkf[t][0]; kf[t][1] = nkf[t][1]; }
#pragma unroll
    for (int dt = 0; dt < 4; dt++) vfA[dt] = vfB[dt];

    // ---- tiles 1..nt-1 ----
    for (int kt = 32; kt <= qmax; kt += 32) {
        if (kt + 32 <= qmax) loadK(kt + 32, nkf);
        loadV(kt, vfB);                  // V(kt), consumed next iter / epilogue
        qk(kf, s);                       // MFMA (independent of prev tile)
        pv(vfA, pfp);                    // MFMA: prev-tile PV, before rescale
        pfp = softmax(s, kt, kt + 32 > qmax);
#pragma unroll
        for (int t = 0; t < 2; t++) { kf[t][0] = nkf[t][0]; kf[t][1] = nkf[t][1]; }
#pragma unroll
        for (int dt = 0; dt < 4; dt++) vfA[dt] = vfB[dt];
    }
    pv(vfA, pfp);                        // epilogue PV of last tile

    const int b = bh >> 4, h = bh & 15;
    float lt = ls;
    lt += __shfl_xor(lt, 16, 64);
    lt += __shfl_xor(lt, 32, 64);
    float inv = 1.f / lt;
    bf16* yp = y + ((size_t)(b * 2048 + qrow)) * 1024 + h * 64 + 4 * lg;
#pragma unroll
    for (int dt = 0; dt < 4; dt++) {
        *(ushort4*)(yp + 16 * dt) = make_ushort4(
            bb(o[dt][0] * inv), bb(o[dt][1] * inv),
            bb(o[dt][2] * inv), bb(o[dt][3] * inv));
    }
}

// ---------- proj GEMM (m97 structure): out = y @ Wproj + bproj (fp32 out) ----------
__global__ __launch_bounds__(256) void k_gemm_proj(
    const bf16* __restrict__ A, const bf16* __restrict__ Bt,
    const float* __restrict__ bias, float* __restrict__ out) {
    __shared__ bf16 lA[128 * 32];
    __shared__ bf16 lB[128 * 32];
    const int tid = threadIdx.x;
    const int wave = tid >> 6, lane = tid & 63;
    const int wm = wave >> 1, wn = wave & 1;
    const int l16 = lane & 15, lg = lane >> 4;
    const int m0 = blockIdx.y * 128, n0 = blockIdx.x * 128;

    f32x4 acc[4][4];
#pragma unroll
    for (int i = 0; i < 4; i++)
#pragma unroll
        for (int j = 0; j < 4; j++) acc[i][j] = (f32x4){0.f, 0.f, 0.f, 0.f};

    const bf16* gA = A + (size_t)(m0 + wave * 32 + (lane >> 2)) * 1024 + (lane & 3) * 8;
    const bf16* gB = Bt + (size_t)(n0 + wave * 32 + (lane >> 2)) * 1024 + (lane & 3) * 8;
    bf16* sA = lA + wave * 1024;
    bf16* sB = lB + wave * 1024;

    for (int k0 = 0; k0 < 1024; k0 += 32) {
        __syncthreads();
        gload16(sA, gA + k0);
        gload16(sA + 512, gA + (size_t)16 * 1024 + k0);
        gload16(sB, gB + k0);
        gload16(sB + 512, gB + (size_t)16 * 1024 + k0);
        __syncthreads();
        bf16x8 af[4], bfr[4];
#pragma unroll
        for (int mi = 0; mi < 4; mi++)
            af[mi] = *(const bf16x8*)(lA + (wm * 64 + mi * 16 + l16) * 32 + lg * 8);
#pragma unroll
        for (int nj = 0; nj < 4; nj++)
            bfr[nj] = *(const bf16x8*)(lB + (wn * 64 + nj * 16 + l16) * 32 + lg * 8);
#pragma unroll
        for (int mi = 0; mi < 4; mi++)
#pragma unroll
            for (int nj = 0; nj < 4; nj++)
                acc[mi][nj] = MFMA16(af[mi], bfr[nj], acc[mi][nj]);
    }

#pragma unroll
    for (int mi = 0; mi < 4; mi++) {
        int mbase = m0 + wm * 64 + mi * 16 + lg * 4;
#pragma unroll
        for (int nj = 0; nj < 4; nj++) {
            int n = n0 + wn * 64 + nj * 16 + l16;
#pragma unroll
            for (int r = 0; r < 4; r++) {
                out[(size_t)(mbase + r) * 1024 + n] = acc[mi][nj][r] + bias[n];
            }
        }
    }
}

// ---------- launch ----------
extern "C" void kernel_launch(void* const* d_in, const int* in_sizes, int n_in,
                              void* d_out, int out_size, void* d_ws, size_t ws_size,
                              hipStream_t stream) {
    const float* x = (const float*)d_in[0];
    const float* Wqkv = (const float*)d_in[1];
    const float* bqkv = (const float*)d_in[2];
    const float* Wproj = (const float*)d_in[3];
    const float* bproj = (const float*)d_in[4];
    float* out = (float*)d_out;

    char* ws = (char*)d_ws;
    bf16* xb = (bf16*)ws;      ws += (size_t)BT * C_ * 2;
    bf16* wqkvT = (bf16*)ws;   ws += (size_t)N3 * C_ * 2;
    bf16* wprojT = (bf16*)ws;  ws += (size_t)C_ * C_ * 2;
    bf16* qb = (bf16*)ws;      ws += (size_t)B_ * H_ * T_ * D_ * 2;
    bf16* kb = (bf16*)ws;      ws += (size_t)B_ * H_ * T_ * D_ * 2;
    bf16* vtb = (bf16*)ws;     ws += (size_t)B_ * H_ * T_ * D_ * 2;
    bf16* yb = (bf16*)ws;      ws += (size_t)BT * C_ * 2;
    float* ct = (float*)ws;    ws += (size_t)T_ * 32 * 4;
    float* st = (float*)ws;    ws += (size_t)T_ * 32 * 4;

    hipLaunchKernelGGL(k_transpose_w, dim3(N3 / 32, C_ / 32), dim3(256), 0, stream,
                       Wqkv, wqkvT, C_, N3);
    hipLaunchKernelGGL(k_transpose_w, dim3(C_ / 32, C_ / 32), dim3(256), 0, stream,
                       Wproj, wprojT, C_, C_);
    hipLaunchKernelGGL(k_convert_x, dim3((BT * C_ / 4) / 256), dim3(256), 0, stream,
                       x, xb, BT * C_ / 4);
    hipLaunchKernelGGL(k_rope_table, dim3((T_ * 32) / 256), dim3(256), 0, stream, ct, st);
    hipLaunchKernelGGL(k_gemm_qkv, dim3(N3 / 128, BT / 128), dim3(256), 0, stream,
                       xb, wqkvT, bqkv, ct, st, qb, kb, vtb);
    hipLaunchKernelGGL(k_attn, dim3(32, B_ * H_), dim3(256), 0, stream,
                       qb, kb, vtb, yb);
    hipLaunchKernelGGL(k_gemm_proj, dim3(C_ / 128, BT / 128), dim3(256), 0, stream,
                       yb, wprojT, bproj, out);
}

// Round 10
// 217.174 us; speedup vs baseline: 1.3188x; 1.3188x over previous
//
#include <hip/hip_runtime.h>
#include <hip/hip_bf16.h>

typedef __hip_bfloat16 bf16;
typedef __attribute__((ext_vector_type(8))) __bf16 bf16x8;
typedef __attribute__((ext_vector_type(4))) __bf16 bf16x4;
typedef __attribute__((ext_vector_type(4))) float f32x4;
typedef unsigned short u16;

#define MFMA16(a, b, c) __builtin_amdgcn_mfma_f32_16x16x32_bf16((a), (b), (c), 0, 0, 0)

static constexpr int B_ = 2, T_ = 2048, C_ = 1024, H_ = 16, D_ = 64;
static constexpr int BT = B_ * T_;   // 4096
static constexpr int N3 = 3 * C_;    // 3072

__device__ __forceinline__ void gload16(void* lds, const void* g) {
    __builtin_amdgcn_global_load_lds(
        (const __attribute__((address_space(1))) unsigned int*)g,
        (__attribute__((address_space(3))) unsigned int*)lds, 16, 0, 0);
}

__device__ __forceinline__ u16 bb(float x) {
    return __builtin_bit_cast(u16, __float2bfloat16(x));
}

// ---------- prep kernels ----------

// src (K rows, N cols) fp32 -> dst (N rows, K cols) bf16, tiled via LDS
__global__ void k_transpose_w(const float* __restrict__ src, bf16* __restrict__ dst,
                              int K, int N) {
    __shared__ float t[32][33];
    int bx = blockIdx.x * 32;  // n offset
    int by = blockIdx.y * 32;  // k offset
    int tx = threadIdx.x & 31, ty = threadIdx.x >> 5;  // 256 thr: ty 0..7
#pragma unroll
    for (int i = 0; i < 32; i += 8)
        t[ty + i][tx] = src[(size_t)(by + ty + i) * N + bx + tx];
    __syncthreads();
#pragma unroll
    for (int i = 0; i < 32; i += 8)
        dst[(size_t)(bx + ty + i) * K + by + tx] = __float2bfloat16(t[tx][ty + i]);
}

__global__ void k_convert_x(const float* __restrict__ src, bf16* __restrict__ dst, int n4) {
    int i = blockIdx.x * 256 + threadIdx.x;
    if (i >= n4) return;
    float4 v = reinterpret_cast<const float4*>(src)[i];
    dst[4 * i + 0] = __float2bfloat16(v.x);
    dst[4 * i + 1] = __float2bfloat16(v.y);
    dst[4 * i + 2] = __float2bfloat16(v.z);
    dst[4 * i + 3] = __float2bfloat16(v.w);
}

// cos/sin tables, (T, 32) each: ang = t * 10000^(-f/32)
__global__ void k_rope_table(float* __restrict__ ct, float* __restrict__ st) {
    int i = blockIdx.x * 256 + threadIdx.x;  // t*32 + f
    if (i >= T_ * 32) return;
    int t = i >> 5, f = i & 31;
    float invf = exp2f(-(float)f * 0.4152410118609203f);  // 10000^(-f/32)
    float ang = (float)t * invf;
    ct[i] = cosf(ang);
    st[i] = sinf(ang);
}

// ---------- QKV GEMM (m97 structure: global_load_lds w=16, linear LDS) ----------
__global__ __launch_bounds__(256) void k_gemm_qkv(
    const bf16* __restrict__ A, const bf16* __restrict__ Bt,
    const float* __restrict__ bias,
    const float* __restrict__ ct, const float* __restrict__ st,
    bf16* __restrict__ q, bf16* __restrict__ kk, bf16* __restrict__ vt) {
    __shared__ bf16 lA[128 * 32];
    __shared__ bf16 lB[128 * 32];
    const int tid = threadIdx.x;
    const int wave = tid >> 6, lane = tid & 63;
    const int wm = wave >> 1, wn = wave & 1;
    const int l16 = lane & 15, lg = lane >> 4;
    const int m0 = blockIdx.y * 128, n0 = blockIdx.x * 128;

    f32x4 acc[4][4];
#pragma unroll
    for (int i = 0; i < 4; i++)
#pragma unroll
        for (int j = 0; j < 4; j++) acc[i][j] = (f32x4){0.f, 0.f, 0.f, 0.f};

    const bf16* gA = A + (size_t)(m0 + wave * 32 + (lane >> 2)) * 1024 + (lane & 3) * 8;
    const bf16* gB = Bt + (size_t)(n0 + wave * 32 + (lane >> 2)) * 1024 + (lane & 3) * 8;
    bf16* sA = lA + wave * 1024;
    bf16* sB = lB + wave * 1024;

    for (int k0 = 0; k0 < 1024; k0 += 32) {
        __syncthreads();
        gload16(sA, gA + k0);
        gload16(sA + 512, gA + (size_t)16 * 1024 + k0);
        gload16(sB, gB + k0);
        gload16(sB + 512, gB + (size_t)16 * 1024 + k0);
        __syncthreads();
        bf16x8 af[4], bfr[4];
#pragma unroll
        for (int mi = 0; mi < 4; mi++)
            af[mi] = *(const bf16x8*)(lA + (wm * 64 + mi * 16 + l16) * 32 + lg * 8);
#pragma unroll
        for (int nj = 0; nj < 4; nj++)
            bfr[nj] = *(const bf16x8*)(lB + (wn * 64 + nj * 16 + l16) * 32 + lg * 8);
#pragma unroll
        for (int mi = 0; mi < 4; mi++)
#pragma unroll
            for (int nj = 0; nj < 4; nj++)
                acc[mi][nj] = MFMA16(af[mi], bfr[nj], acc[mi][nj]);
    }

    // epilogue: bias + RoPE + scatter
    const int b = m0 >> 11;
#pragma unroll
    for (int mi = 0; mi < 4; mi++) {
        int mbase = m0 + wm * 64 + mi * 16 + lg * 4;
#pragma unroll
        for (int nj = 0; nj < 4; nj++) {
            int n = n0 + wn * 64 + nj * 16 + l16;
            int which = n >> 10;        // 0=q 1=k 2=v (uniform per block)
            int nq = n & 1023;
            int h = nq >> 6, d = nq & 63;
#pragma unroll
            for (int r = 0; r < 4; r++) {
                int m = mbase + r;
                int t = m & 2047;
                float v = acc[mi][nj][r] + bias[n];
                if (which == 2) {
                    vt[((size_t)(b * 16 + h) * 64 + d) * 2048 + t] = __float2bfloat16(v);
                } else {
                    float pv = acc[mi][nj ^ 2][r] + bias[n ^ 32];  // partner d^32, same lane
                    float c = ct[t * 32 + (d & 31)];
                    float s = st[t * 32 + (d & 31)];
                    float rh = (d < 32) ? -pv : pv;
                    float o = v * c + rh * s;
                    bf16* dst = (which == 0) ? q : kk;
                    dst[((size_t)(b * 16 + h) * 2048 + t) * 64 + d] = __float2bfloat16(o);
                }
            }
        }
    }
}

// ---------- flash attention: R8 compute, 1-wave blocks for dynamic balance ----------
// Compute identical to R8 (PASS, absmax 0.0156): swapped 16x16x32 QK^T, as-owned-P
// + permuted-V PV, e-domain always-rescale softmax. Changes are scheduling only:
//   - 2048 one-wave blocks (32 q-rows each): 8x oversubscription -> HW backfills tail
//   - id = (63-strip)*32 + bh: heavy strips dispatch first; id%8 == bh%8 pins each
//     head's strips to one XCD -> 4 heads x 512KB = 2MB K/V resident per 4MB L2.
__global__ __launch_bounds__(64, 4) void k_attn(
    const bf16* __restrict__ qg, const bf16* __restrict__ kg,
    const bf16* __restrict__ vtg, bf16* __restrict__ y) {
    const int lane = threadIdx.x & 63;
    const int l16 = lane & 15, lg = lane >> 4;
    const int id = blockIdx.x;
    const int bh = id & 31;
    const int strip = 63 - (id >> 5);       // heavy first
    const int q0 = strip * 32;
    const bf16* qh = qg + (size_t)bh * (2048 * 64);
    const bf16* kh = kg + (size_t)bh * (2048 * 64);
    const bf16* vh = vtg + (size_t)bh * (64 * 2048);

    // Q B-frags (2 q-groups x 2 d-halves), raw bf16
    bf16x8 qf[2][2];
#pragma unroll
    for (int g = 0; g < 2; g++)
#pragma unroll
        for (int h = 0; h < 2; h++)
            qf[g][h] = *(const bf16x8*)(qh + (size_t)(q0 + 16 * g + l16) * 64 + 32 * h + 8 * lg);

    f32x4 o[2][4];
#pragma unroll
    for (int g = 0; g < 2; g++)
#pragma unroll
        for (int dt = 0; dt < 4; dt++) o[g][dt] = (f32x4){0.f, 0.f, 0.f, 0.f};
    float mm[2] = {-1e30f, -1e30f}, ls[2] = {0.f, 0.f};

    bf16x8 kf[2][2], vf[4];
    auto loadK = [&](int kt, bf16x8 kfo[2][2]) {
#pragma unroll
        for (int t = 0; t < 2; t++) {
            const bf16* kp = kh + (size_t)(kt + 16 * t + l16) * 64 + 8 * lg;
            kfo[t][0] = *(const bf16x8*)(kp);
            kfo[t][1] = *(const bf16x8*)(kp + 32);
        }
    };
    auto loadV = [&](int kt, bf16x8 vfo[4]) {
#pragma unroll
        for (int dt = 0; dt < 4; dt++) {
            const bf16* vp = vh + (size_t)(16 * dt + l16) * 2048 + kt;
            bf16x4 lo = *(const bf16x4*)(vp + 4 * lg);
            bf16x4 hi = *(const bf16x4*)(vp + 16 + 4 * lg);
            vfo[dt] = __builtin_shufflevector(lo, hi, 0, 1, 2, 3, 4, 5, 6, 7);
        }
    };

    const f32x4 z = (f32x4){0.f, 0.f, 0.f, 0.f};
    auto tile = [&](bf16x8 kfi[2][2], bf16x8 vfi[4], bool diag) {
        f32x4 s[2][2];
#pragma unroll
        for (int g = 0; g < 2; g++)
#pragma unroll
            for (int t = 0; t < 2; t++) {
                f32x4 acc = MFMA16(kfi[t][0], qf[g][0], z);
                s[g][t] = MFMA16(kfi[t][1], qf[g][1], acc);
            }
#pragma unroll
        for (int g = 0; g < 2; g++) {
            float p[8];
#pragma unroll
            for (int t = 0; t < 2; t++)
#pragma unroll
                for (int r = 0; r < 4; r++) {
                    float v = s[g][t][r] * 0.125f;
                    if (diag && (16 * t + 4 * lg + r > 16 * g + l16)) v = -1e30f;
                    p[4 * t + r] = v;
                }
            float pm = p[0];
#pragma unroll
            for (int i = 1; i < 8; i++) pm = fmaxf(pm, p[i]);
            pm = fmaxf(pm, __shfl_xor(pm, 16, 64));
            pm = fmaxf(pm, __shfl_xor(pm, 32, 64));
            float mn = fmaxf(mm[g], pm);
            float al = __expf(mm[g] - mn);
#pragma unroll
            for (int dt = 0; dt < 4; dt++) o[g][dt] *= al;
            ls[g] *= al;
            mm[g] = mn;
            float ps = 0.f;
#pragma unroll
            for (int i = 0; i < 8; i++) {
                p[i] = __expf(p[i] - mn);
                ps += p[i];
            }
            ls[g] += ps;
            bf16x8 pf;
#pragma unroll
            for (int j = 0; j < 8; j++)
                pf[j] = __builtin_bit_cast(__bf16, __float2bfloat16(p[j]));
#pragma unroll
            for (int dt = 0; dt < 4; dt++) o[g][dt] = MFMA16(vfi[dt], pf, o[g][dt]);
        }
    };

    loadK(0, kf);
    loadV(0, vf);
    for (int kt = 32; kt <= q0; kt += 32) {
        bf16x8 nkf[2][2], nvf[4];
        loadK(kt, nkf);          // prefetch next tile
        loadV(kt, nvf);
        tile(kf, vf, false);
#pragma unroll
        for (int t = 0; t < 2; t++) { kf[t][0] = nkf[t][0]; kf[t][1] = nkf[t][1]; }
#pragma unroll
        for (int dt = 0; dt < 4; dt++) vf[dt] = nvf[dt];
    }
    tile(kf, vf, true);          // diagonal tile

    const int b = bh >> 4, h = bh & 15;
#pragma unroll
    for (int g = 0; g < 2; g++) {
        float lt = ls[g];
        lt += __shfl_xor(lt, 16, 64);
        lt += __shfl_xor(lt, 32, 64);
        float inv = 1.f / lt;
        bf16* yp = y + ((size_t)(b * 2048 + q0 + 16 * g + l16)) * 1024 + h * 64 + 4 * lg;
#pragma unroll
        for (int dt = 0; dt < 4; dt++) {
            *(ushort4*)(yp + 16 * dt) = make_ushort4(
                bb(o[g][dt][0] * inv), bb(o[g][dt][1] * inv),
                bb(o[g][dt][2] * inv), bb(o[g][dt][3] * inv));
        }
    }
}

// ---------- proj GEMM (m97 structure): out = y @ Wproj + bproj (fp32 out) ----------
__global__ __launch_bounds__(256) void k_gemm_proj(
    const bf16* __restrict__ A, const bf16* __restrict__ Bt,
    const float* __restrict__ bias, float* __restrict__ out) {
    __shared__ bf16 lA[128 * 32];
    __shared__ bf16 lB[128 * 32];
    const int tid = threadIdx.x;
    const int wave = tid >> 6, lane = tid & 63;
    const int wm = wave >> 1, wn = wave & 1;
    const int l16 = lane & 15, lg = lane >> 4;
    const int m0 = blockIdx.y * 128, n0 = blockIdx.x * 128;

    f32x4 acc[4][4];
#pragma unroll
    for (int i = 0; i < 4; i++)
#pragma unroll
        for (int j = 0; j < 4; j++) acc[i][j] = (f32x4){0.f, 0.f, 0.f, 0.f};

    const bf16* gA = A + (size_t)(m0 + wave * 32 + (lane >> 2)) * 1024 + (lane & 3) * 8;
    const bf16* gB = Bt + (size_t)(n0 + wave * 32 + (lane >> 2)) * 1024 + (lane & 3) * 8;
    bf16* sA = lA + wave * 1024;
    bf16* sB = lB + wave * 1024;

    for (int k0 = 0; k0 < 1024; k0 += 32) {
        __syncthreads();
        gload16(sA, gA + k0);
        gload16(sA + 512, gA + (size_t)16 * 1024 + k0);
        gload16(sB, gB + k0);
        gload16(sB + 512, gB + (size_t)16 * 1024 + k0);
        __syncthreads();
        bf16x8 af[4], bfr[4];
#pragma unroll
        for (int mi = 0; mi < 4; mi++)
            af[mi] = *(const bf16x8*)(lA + (wm * 64 + mi * 16 + l16) * 32 + lg * 8);
#pragma unroll
        for (int nj = 0; nj < 4; nj++)
            bfr[nj] = *(const bf16x8*)(lB + (wn * 64 + nj * 16 + l16) * 32 + lg * 8);
#pragma unroll
        for (int mi = 0; mi < 4; mi++)
#pragma unroll
            for (int nj = 0; nj < 4; nj++)
                acc[mi][nj] = MFMA16(af[mi], bfr[nj], acc[mi][nj]);
    }

#pragma unroll
    for (int mi = 0; mi < 4; mi++) {
        int mbase = m0 + wm * 64 + mi * 16 + lg * 4;
#pragma unroll
        for (int nj = 0; nj < 4; nj++) {
            int n = n0 + wn * 64 + nj * 16 + l16;
#pragma unroll
            for (int r = 0; r < 4; r++) {
                out[(size_t)(mbase + r) * 1024 + n] = acc[mi][nj][r] + bias[n];
            }
        }
    }
}

// ---------- launch ----------
extern "C" void kernel_launch(void* const* d_in, const int* in_sizes, int n_in,
                              void* d_out, int out_size, void* d_ws, size_t ws_size,
                              hipStream_t stream) {
    const float* x = (const float*)d_in[0];
    const float* Wqkv = (const float*)d_in[1];
    const float* bqkv = (const float*)d_in[2];
    const float* Wproj = (const float*)d_in[3];
    const float* bproj = (const float*)d_in[4];
    float* out = (float*)d_out;

    char* ws = (char*)d_ws;
    bf16* xb = (bf16*)ws;      ws += (size_t)BT * C_ * 2;
    bf16* wqkvT = (bf16*)ws;   ws += (size_t)N3 * C_ * 2;
    bf16* wprojT = (bf16*)ws;  ws += (size_t)C_ * C_ * 2;
    bf16* qb = (bf16*)ws;      ws += (size_t)B_ * H_ * T_ * D_ * 2;
    bf16* kb = (bf16*)ws;      ws += (size_t)B_ * H_ * T_ * D_ * 2;
    bf16* vtb = (bf16*)ws;     ws += (size_t)B_ * H_ * T_ * D_ * 2;
    bf16* yb = (bf16*)ws;      ws += (size_t)BT * C_ * 2;
    float* ct = (float*)ws;    ws += (size_t)T_ * 32 * 4;
    float* st = (float*)ws;    ws += (size_t)T_ * 32 * 4;

    hipLaunchKernelGGL(k_transpose_w, dim3(N3 / 32, C_ / 32), dim3(256), 0, stream,
                       Wqkv, wqkvT, C_, N3);
    hipLaunchKernelGGL(k_transpose_w, dim3(C_ / 32, C_ / 32), dim3(256), 0, stream,
                       Wproj, wprojT, C_, C_);
    hipLaunchKernelGGL(k_convert_x, dim3((BT * C_ / 4) / 256), dim3(256), 0, stream,
                       x, xb, BT * C_ / 4);
    hipLaunchKernelGGL(k_rope_table, dim3((T_ * 32) / 256), dim3(256), 0, stream, ct, st);
    hipLaunchKernelGGL(k_gemm_qkv, dim3(N3 / 128, BT / 128), dim3(256), 0, stream,
                       xb, wqkvT, bqkv, ct, st, qb, kb, vtb);
    hipLaunchKernelGGL(k_attn, dim3(64 * 32), dim3(64), 0, stream,
                       qb, kb, vtb, yb);
    hipLaunchKernelGGL(k_gemm_proj, dim3(C_ / 128, BT / 128), dim3(256), 0, stream,
                       yb, wprojT, bproj, out);
}